// Round 4
// baseline (15110.837 us; speedup 1.0000x reference)
//
#include <hip/hip_runtime.h>
#include <cstdint>

// Problem dims
#define BB   256
#define TT   128
#define HH   512
#define LLAY 4
#define NTAG 74
#define G4   2048   // 4*H
#define K2   1024   // 2*H

typedef short short8 __attribute__((ext_vector_type(8)));
typedef float f32x4  __attribute__((ext_vector_type(4)));
typedef int   i32x4  __attribute__((ext_vector_type(4)));

__device__ __forceinline__ float b2f(short s) {
  union { unsigned u; float f; } c; c.u = ((unsigned)(unsigned short)s) << 16; return c.f;
}
__device__ __forceinline__ short f2b(float f) {
  union { float f; unsigned u; } c; c.f = f;
  unsigned u = c.u + 0x7fffu + ((c.u >> 16) & 1u);
  return (short)(u >> 16);
}
__device__ __forceinline__ float sigm(float x) { return 1.f / (1.f + __expf(-x)); }
__device__ __forceinline__ float tanh_f(float x) {
  x = fminf(fmaxf(x, -15.f), 15.f);
  float e = __expf(2.f * x);
  return (e - 1.f) / (e + 1.f);
}

// ---- coherent (MALL) access helpers: bypass L1/L2 with sc0 sc1 ----
__device__ __forceinline__ void ld8_sc(i32x4* d,
    const short* a0, const short* a1, const short* a2, const short* a3,
    const short* a4, const short* a5, const short* a6, const short* a7) {
  asm volatile(
      "global_load_dwordx4 %0, %8, off sc0 sc1\n\t"
      "global_load_dwordx4 %1, %9, off sc0 sc1\n\t"
      "global_load_dwordx4 %2, %10, off sc0 sc1\n\t"
      "global_load_dwordx4 %3, %11, off sc0 sc1\n\t"
      "global_load_dwordx4 %4, %12, off sc0 sc1\n\t"
      "global_load_dwordx4 %5, %13, off sc0 sc1\n\t"
      "global_load_dwordx4 %6, %14, off sc0 sc1\n\t"
      "global_load_dwordx4 %7, %15, off sc0 sc1\n\t"
      "s_waitcnt vmcnt(0)"
      : "=&v"(d[0]), "=&v"(d[1]), "=&v"(d[2]), "=&v"(d[3]),
        "=&v"(d[4]), "=&v"(d[5]), "=&v"(d[6]), "=&v"(d[7])
      : "v"(a0), "v"(a1), "v"(a2), "v"(a3), "v"(a4), "v"(a5), "v"(a6), "v"(a7)
      : "memory");
}
__device__ __forceinline__ void st2_sc(short* p, int v) {
  asm volatile("global_store_short %0, %1, off sc0 sc1" :: "v"(p), "v"(v) : "memory");
}

// Fence-free grid barrier through MALL-coherent flags (no L2 inv/writeback).
__device__ __forceinline__ void gbar(unsigned* flags, int target) {
  asm volatile("s_waitcnt vmcnt(0)" ::: "memory");
  __syncthreads();    // drains every wave's vmcnt before flag store
  if (threadIdx.x == 0) {
    int t = target;
    asm volatile("global_store_dword %0, %1, off sc0 sc1"
                 :: "v"(flags + blockIdx.x), "v"(t) : "memory");
  }
  if (threadIdx.x < 64) {
    const unsigned* p = flags + threadIdx.x * 8;
    for (;;) {
      i32x4 a, b;
      asm volatile(
          "global_load_dwordx4 %0, %2, off sc0 sc1\n\t"
          "global_load_dwordx4 %1, %3, off sc0 sc1\n\t"
          "s_waitcnt vmcnt(0)"
          : "=&v"(a), "=&v"(b) : "v"(p), "v"(p + 4) : "memory");
      int mn = min(min(min(a[0], a[1]), min(a[2], a[3])),
                   min(min(b[0], b[1]), min(b[2], b[3])));
      #pragma unroll
      for (int off = 32; off > 0; off >>= 1) mn = min(mn, __shfl_xor(mn, off));
      if (mn >= target) break;
    }
  }
  __syncthreads();
}

// ---------------- prep kernels ----------------

// Wcat[which][l][n'][k] bf16, n' = (h>>4)*64 + gate*16 + (h&15); k<512 from Wih, else Whh
__global__ void prep_lstm_w(const float* __restrict__ eWih, const float* __restrict__ eWhh,
                            const float* __restrict__ dWih, const float* __restrict__ dWhh,
                            short* __restrict__ WcatE, short* __restrict__ WcatD) {
  int idx = blockIdx.x * 256 + threadIdx.x;   // 2*4*2048*1024 = 2^24 exact
  int k = idx & 1023;
  int np = (idx >> 10) & 2047;
  int l = (idx >> 21) & 3;
  int which = idx >> 23;
  int gate = (np >> 4) & 3;
  int h = ((np >> 6) << 4) | (np & 15);
  int srow = gate * HH + h;
  const float* Wih = which ? dWih : eWih;
  const float* Whh = which ? dWhh : eWhh;
  float v = (k < HH) ? Wih[(size_t)(l * G4 + srow) * HH + k]
                     : Whh[(size_t)(l * G4 + srow) * HH + (k - HH)];
  short* dst = which ? WcatD : WcatE;
  dst[(size_t)(l * G4 + np) * K2 + k] = f2b(v);
}

__global__ void prep_misc(const float* __restrict__ ebih, const float* __restrict__ ebhh,
                          const float* __restrict__ dbih, const float* __restrict__ dbhh,
                          const float* __restrict__ bq, const float* __restrict__ bk,
                          const float* __restrict__ bv,
                          const float* __restrict__ Wtag, const float* __restrict__ btag,
                          float* __restrict__ bE, float* __restrict__ bD,
                          float* __restrict__ bqkv, short* __restrict__ Wt,
                          float* __restrict__ btg) {
  int idx = blockIdx.x * 256 + threadIdx.x;
  if (idx < 16384) {                                    // combined biases, permuted
    int np = idx & 2047; int l = (idx >> 11) & 3; int which = idx >> 13;
    int gate = (np >> 4) & 3; int h = ((np >> 6) << 4) | (np & 15);
    int srow = gate * HH + h;
    const float* bih = which ? dbih : ebih; const float* bhh = which ? dbhh : ebhh;
    (which ? bD : bE)[l * G4 + np] = bih[l * G4 + srow] + bhh[l * G4 + srow];
  } else if (idx < 16384 + 1536) {
    int j = idx - 16384;
    bqkv[j] = (j < 512) ? bq[j] : (j < 1024 ? bk[j - 512] : bv[j - 1024]);
  } else if (idx < 16384 + 1536 + 80 * 512) {           // Wt[80][512] (zero-padded rows)
    int j = idx - (16384 + 1536);
    int c = j >> 9, k = j & 511;
    Wt[j] = f2b(c < NTAG ? Wtag[(size_t)c * HH + k] : 0.f);
  } else if (idx < 16384 + 1536 + 80 * 512 + 80) {
    int c = idx - (16384 + 1536 + 80 * 512);
    btg[c] = (c < NTAG) ? btag[c] : 0.f;
  }
}

__global__ void prep_qkvw(const float* __restrict__ Wq, const float* __restrict__ Wk,
                          const float* __restrict__ Wv, short* __restrict__ Wqkv) {
  int idx = blockIdx.x * 256 + threadIdx.x;   // 1536*512
  int k = idx & 511; int n = idx >> 9;
  const float* W = (n < 512) ? Wq : (n < 1024 ? Wk : Wv);
  Wqkv[idx] = f2b(W[(size_t)(n & 511) * HH + k]);
}

__global__ void prep_emb(const int* __restrict__ ids, const float* __restrict__ emb,
                         short* __restrict__ X) {
  int idx = blockIdx.x * 256 + threadIdx.x;   // T*B*H = 2^24, layout [t][b][h]
  int h = idx & 511; int b = (idx >> 9) & 255; int t = idx >> 17;
  int tok = ids[b * TT + t];
  X[idx] = f2b(emb[(size_t)tok * HH + h]);
}

// ---------------- persistent LSTM: encoder wavefront + decoder ----------------
// 512 blocks x 256 threads, co-resident (2 blocks/CU). Hand-rolled MALL
// barrier; h-state via sc0sc1; weights L2-cached with XCD-affine tile
// ownership (bid%8 == XCD under round-robin dispatch) so each XCD's weight
// working set (~2 MB) stays resident in its 4 MiB L2 across all phases.
__global__ __launch_bounds__(256, 2) void lstm_coop(
    const short* __restrict__ WE, const short* __restrict__ WD,
    const float* __restrict__ bEc, const float* __restrict__ bDc,
    const short* __restrict__ X, short* __restrict__ hE,
    short* __restrict__ hD, float* __restrict__ cbuf, short* __restrict__ dec,
    unsigned* __restrict__ flags) {
  const int bid = blockIdx.x;
  const int wave = threadIdx.x >> 6, lane = threadIdx.x & 63;
  const int ll = lane & 15, quad = lane >> 4;
  const size_t SL = (size_t)BB * HH;
  const int xcd = bid & 7, slot = bid >> 3;

  __shared__ __align__(16) char smem[70656];
  short* eA = (short*)smem;                 // encoder: [4 waves][16 rows][520]
  short* dA = (short*)smem;                 // decoder: [16 rows][1040]
  float* part = (float*)(smem + 33280);     // decoder: [4][4][16][16]

  int phase = 0;

  // ================= encoder wavefront: 131 diagonals =================
  {
    // XCD-affine: layer = xcd/2; n-half = xcd&1. Per-XCD weights: 16x128KB = 2MB.
    const int l = xcd >> 1;
    const int tm = slot >> 4, tn = (xcd & 1) * 16 + (slot & 15);
    const int m0 = tm * 64, n0 = tn * 64;
    short* Aw = eA + wave * 16 * 520;
    for (int d = 0; d < TT + LLAY - 1; ++d) {
      const int t = d - l;
      if (t >= 0 && t < TT) {
        const short* W = WE + (size_t)l * G4 * K2;
        const float* bcp = bEc + l * G4;
        const short* hin = hE + ((size_t)((d - 1) & 1) * LLAY + l) * SL;
        const short* xs = (l == 0) ? (X + (size_t)t * SL)
                                   : (hE + ((size_t)((d - 1) & 1) * LLAY + (l - 1)) * SL);
        short* hout = hE + ((size_t)(d & 1) * LLAY + l) * SL;
        short* hout2 = (t == TT - 1) ? (hD + ((size_t)LLAY + l) * SL) : nullptr;
        float* cb = cbuf + (size_t)l * SL;

        f32x4 acc[4] = {};
        const short* bp = W + (size_t)(n0 + ll) * K2 + quad * 8;

        // ---- k-half 0: x (stage via MALL, wave-private LDS region) ----
        {
          i32x4 dr[8];
          const short* g = xs + (size_t)(m0 + wave * 16) * HH + lane * 8;
          ld8_sc(dr, g, g + HH, g + 2 * HH, g + 3 * HH,
                 g + 4 * HH, g + 5 * HH, g + 6 * HH, g + 7 * HH);
          #pragma unroll
          for (int i = 0; i < 8; ++i) *(i32x4*)(Aw + i * 520 + lane * 8) = dr[i];
          const short* g2 = g + 8 * HH;
          ld8_sc(dr, g2, g2 + HH, g2 + 2 * HH, g2 + 3 * HH,
                 g2 + 4 * HH, g2 + 5 * HH, g2 + 6 * HH, g2 + 7 * HH);
          #pragma unroll
          for (int i = 0; i < 8; ++i) *(i32x4*)(Aw + (8 + i) * 520 + lane * 8) = dr[i];
        }
        #pragma unroll 4
        for (int ks = 0; ks < 16; ++ks) {
          short8 a = *(const short8*)(Aw + ll * 520 + ks * 32 + quad * 8);
          #pragma unroll
          for (int f = 0; f < 4; ++f)
            acc[f] = __builtin_amdgcn_mfma_f32_16x16x32_bf16(
                a, *(const short8*)(bp + (size_t)f * 16 * K2 + ks * 32), acc[f], 0, 0, 0);
        }
        // ---- k-half 1: h ----
        {
          i32x4 dr[8];
          const short* g = hin + (size_t)(m0 + wave * 16) * HH + lane * 8;
          ld8_sc(dr, g, g + HH, g + 2 * HH, g + 3 * HH,
                 g + 4 * HH, g + 5 * HH, g + 6 * HH, g + 7 * HH);
          #pragma unroll
          for (int i = 0; i < 8; ++i) *(i32x4*)(Aw + i * 520 + lane * 8) = dr[i];
          const short* g2 = g + 8 * HH;
          ld8_sc(dr, g2, g2 + HH, g2 + 2 * HH, g2 + 3 * HH,
                 g2 + 4 * HH, g2 + 5 * HH, g2 + 6 * HH, g2 + 7 * HH);
          #pragma unroll
          for (int i = 0; i < 8; ++i) *(i32x4*)(Aw + (8 + i) * 520 + lane * 8) = dr[i];
        }
        #pragma unroll 4
        for (int ks = 0; ks < 16; ++ks) {
          short8 a = *(const short8*)(Aw + ll * 520 + ks * 32 + quad * 8);
          #pragma unroll
          for (int f = 0; f < 4; ++f)
            acc[f] = __builtin_amdgcn_mfma_f32_16x16x32_bf16(
                a, *(const short8*)(bp + 512 + (size_t)f * 16 * K2 + ks * 32), acc[f], 0, 0, 0);
        }
        // ---- fused LSTM cell epilogue (c is block-private: cached) ----
        const float bg0 = bcp[n0 + ll], bg1 = bcp[n0 + 16 + ll];
        const float bg2 = bcp[n0 + 32 + ll], bg3 = bcp[n0 + 48 + ll];
        const int hcol = tn * 16 + ll;
        #pragma unroll
        for (int r = 0; r < 4; ++r) {
          int row = m0 + wave * 16 + quad * 4 + r;
          float iv = acc[0][r] + bg0, fv = acc[1][r] + bg1;
          float gv = acc[2][r] + bg2, ov = acc[3][r] + bg3;
          float co = cb[(size_t)row * HH + hcol];
          float cn = sigm(fv) * co + sigm(iv) * tanh_f(gv);
          float hn = sigm(ov) * tanh_f(cn);
          cb[(size_t)row * HH + hcol] = cn;
          short hb = f2b(hn);
          st2_sc(hout + (size_t)row * HH + hcol, (int)(unsigned short)hb);
          if (hout2) st2_sc(hout2 + (size_t)row * HH + hcol, (int)(unsigned short)hb);
        }
      }
      ++phase;
      gbar(flags, phase);
    }
  }

  // push encoder's cached dirty c lines to MALL before ownership changes
  asm volatile("buffer_wbl2 sc1" ::: "memory");
  ++phase;
  gbar(flags, phase);

  // ================= decoder: 512 sequential layer-steps =================
  {
    // XCD-affine: xcd owns ntile in [xcd*4, xcd*4+4). Per-XCD weights
    // across all 4 layers: 4*4*128KB = 2MB — L2-resident for all phases.
    const int mrow = slot >> 2, ntile = xcd * 4 + (slot & 3);
    const int m0 = mrow * 16;
    for (int p = 0; p < TT * LLAY; ++p) {
      const int t = p >> 2, l = p & 3;
      const short* W = WD + (size_t)l * G4 * K2;
      const float* bcp = bDc + l * G4;
      const short* hin = hD + ((size_t)((t + 1) & 1) * LLAY + l) * SL;
      const short* xs = (l == 0) ? (hD + ((size_t)((t + 1) & 1) * LLAY + 3) * SL)
                                 : (hD + ((size_t)(t & 1) * LLAY + (l - 1)) * SL);
      short* hout = hD + ((size_t)(t & 1) * LLAY + l) * SL;
      float* cb = cbuf + (size_t)l * SL;

      // stage A = [x | h] 16 rows x 1024 via MALL into LDS (cross-wave)
      {
        i32x4 dr[8];
        const short* gx = xs + (size_t)(m0 + wave * 4) * HH + lane * 8;
        const short* gh = hin + (size_t)(m0 + wave * 4) * HH + lane * 8;
        ld8_sc(dr, gx, gx + HH, gx + 2 * HH, gx + 3 * HH,
               gh, gh + HH, gh + 2 * HH, gh + 3 * HH);
        #pragma unroll
        for (int i = 0; i < 4; ++i) *(i32x4*)(dA + (wave * 4 + i) * 1040 + lane * 8) = dr[i];
        #pragma unroll
        for (int i = 0; i < 4; ++i) *(i32x4*)(dA + (wave * 4 + i) * 1040 + 512 + lane * 8) = dr[4 + i];
      }
      __syncthreads();

      // split-K: wave w covers k-quarter w*256 (x halves then h halves)
      f32x4 acc[4] = {};
      const short* bp = W + (size_t)(ntile * 64 + ll) * K2 + wave * 256 + quad * 8;
      #pragma unroll
      for (int ks = 0; ks < 8; ++ks) {
        short8 a = *(const short8*)(dA + ll * 1040 + wave * 256 + ks * 32 + quad * 8);
        #pragma unroll
        for (int f = 0; f < 4; ++f)
          acc[f] = __builtin_amdgcn_mfma_f32_16x16x32_bf16(
              a, *(const short8*)(bp + (size_t)f * 16 * K2 + ks * 32), acc[f], 0, 0, 0);
      }
      #pragma unroll
      for (int f = 0; f < 4; ++f)
        #pragma unroll
        for (int r = 0; r < 4; ++r)
          part[((wave * 4 + f) * 16 + quad * 4 + r) * 16 + ll] = acc[f][r];
      __syncthreads();
      {
        const int row = threadIdx.x >> 4, hc = threadIdx.x & 15;
        float g4v[4];
        #pragma unroll
        for (int f = 0; f < 4; ++f) {
          float s = bcp[ntile * 64 + f * 16 + hc];
          #pragma unroll
          for (int w = 0; w < 4; ++w) s += part[((w * 4 + f) * 16 + row) * 16 + hc];
          g4v[f] = s;
        }
        const int brow = m0 + row, hcol = ntile * 16 + hc;
        float co = cb[(size_t)brow * HH + hcol];
        float cn = sigm(g4v[1]) * co + sigm(g4v[0]) * tanh_f(g4v[2]);
        float hn = sigm(g4v[3]) * tanh_f(cn);
        cb[(size_t)brow * HH + hcol] = cn;
        short hb = f2b(hn);
        st2_sc(hout + (size_t)brow * HH + hcol, (int)(unsigned short)hb);
        if (l == 3) dec[((size_t)brow * TT + t) * HH + hcol] = hb;
      }
      ++phase;
      gbar(flags, phase);
    }
  }
}

// ---------------- LayerNorm (in place, bf16) ----------------
__global__ __launch_bounds__(256) void ln_kernel(short* __restrict__ x,
                                                 const float* __restrict__ g,
                                                 const float* __restrict__ bta) {
  int wave = threadIdx.x >> 6, lane = threadIdx.x & 63;
  int row = blockIdx.x * 4 + wave;
  short8 xv = *(const short8*)(x + (size_t)row * HH + lane * 8);
  float xs[8]; float s = 0.f, ss = 0.f;
  #pragma unroll
  for (int j = 0; j < 8; ++j) { xs[j] = b2f(xv[j]); s += xs[j]; ss += xs[j] * xs[j]; }
  #pragma unroll
  for (int off = 1; off < 64; off <<= 1) { s += __shfl_xor(s, off); ss += __shfl_xor(ss, off); }
  float mu = s * (1.f / HH);
  float var = ss * (1.f / HH) - mu * mu;
  float rs = rsqrtf(var + 1e-5f);
  short8 ov;
  #pragma unroll
  for (int j = 0; j < 8; ++j) {
    int k = lane * 8 + j;
    ov[j] = f2b((xs[j] - mu) * rs * g[k] + bta[k]);
  }
  *(short8*)(x + (size_t)row * HH + lane * 8) = ov;
}

// ---------------- QKV projection GEMM ----------------
__global__ __launch_bounds__(256) void gemm_qkv(const short* __restrict__ A,
                                                const short* __restrict__ Wn,
                                                const float* __restrict__ bias,
                                                short* __restrict__ out) {
  int wave = threadIdx.x >> 6, lane = threadIdx.x & 63, ll = lane & 15, quad = lane >> 4;
  int m0 = blockIdx.x * 64 + wave * 16;
  int n0 = blockIdx.y * 64;
  f32x4 acc[4] = {};
  const short* ap = A + (size_t)(m0 + ll) * HH + quad * 8;
  const short* bp = Wn + (size_t)(n0 + ll) * HH + quad * 8;
  #pragma unroll 4
  for (int ks = 0; ks < 16; ++ks) {
    short8 a = *(const short8*)(ap + ks * 32);
    #pragma unroll
    for (int f = 0; f < 4; ++f)
      acc[f] = __builtin_amdgcn_mfma_f32_16x16x32_bf16(a, *(const short8*)(bp + f * 16 * HH + ks * 32), acc[f], 0, 0, 0);
  }
  #pragma unroll
  for (int f = 0; f < 4; ++f) {
    int n = n0 + f * 16 + ll;
    float bv = bias[n];
    #pragma unroll
    for (int r = 0; r < 4; ++r) {
      int row = m0 + quad * 4 + r;
      out[(size_t)row * 1536 + n] = f2b(acc[f][r] + bv);
    }
  }
}

// ---------------- V transpose: Vt[b][h][t] ----------------
__global__ void vtrans(const short* __restrict__ qkv, short* __restrict__ vt) {
  int idx = blockIdx.x * 256 + threadIdx.x;  // 256*512*128 = 2^24
  int t = idx & 127, h = (idx >> 7) & 511, b = idx >> 16;
  vt[idx] = qkv[(size_t)(b * TT + t) * 1536 + 1024 + h];
}

// ---------------- Fused attention per batch ----------------
__global__ __launch_bounds__(256) void attn_kernel(const short* __restrict__ qkv,
                                                   const short* __restrict__ vt,
                                                   short* __restrict__ attno) {
  int b = blockIdx.x;
  int wave = threadIdx.x >> 6, lane = threadIdx.x & 63, ll = lane & 15, quad = lane >> 4;
  __shared__ __align__(16) short P[128][136];
  const short* qb = qkv + (size_t)b * TT * 1536;
  int r0 = wave * 32;

  f32x4 s[2][8] = {};
  for (int ks = 0; ks < 16; ++ks) {
    short8 a0 = *(const short8*)(qb + (size_t)(r0 + ll) * 1536 + ks * 32 + quad * 8);
    short8 a1 = *(const short8*)(qb + (size_t)(r0 + 16 + ll) * 1536 + ks * 32 + quad * 8);
    #pragma unroll
    for (int ct = 0; ct < 8; ++ct) {
      short8 bbv = *(const short8*)(qb + (size_t)(ct * 16 + ll) * 1536 + 512 + ks * 32 + quad * 8);
      s[0][ct] = __builtin_amdgcn_mfma_f32_16x16x32_bf16(a0, bbv, s[0][ct], 0, 0, 0);
      s[1][ct] = __builtin_amdgcn_mfma_f32_16x16x32_bf16(a1, bbv, s[1][ct], 0, 0, 0);
    }
  }
  const float scale = 0.04419417382415922f;  // 1/sqrt(512)
  #pragma unroll
  for (int mt = 0; mt < 2; ++mt) {
    #pragma unroll
    for (int r = 0; r < 4; ++r) {
      float v[8]; float mx = -1e30f;
      #pragma unroll
      for (int ct = 0; ct < 8; ++ct) { v[ct] = s[mt][ct][r] * scale; mx = fmaxf(mx, v[ct]); }
      #pragma unroll
      for (int off = 1; off < 16; off <<= 1) mx = fmaxf(mx, __shfl_xor(mx, off));
      float sum = 0.f;
      #pragma unroll
      for (int ct = 0; ct < 8; ++ct) { v[ct] = __expf(v[ct] - mx); sum += v[ct]; }
      #pragma unroll
      for (int off = 1; off < 16; off <<= 1) sum += __shfl_xor(sum, off);
      float inv = 1.f / sum;
      int row = r0 + mt * 16 + quad * 4 + r;
      #pragma unroll
      for (int ct = 0; ct < 8; ++ct) P[row][ct * 16 + ll] = f2b(v[ct] * inv);
    }
  }
  __syncthreads();

  const short* vtb = vt + (size_t)b * HH * TT;
  for (int hc = 0; hc < 4; ++hc) {
    f32x4 o[2][8] = {};
    #pragma unroll
    for (int kp = 0; kp < 4; ++kp) {
      short8 a0 = *(const short8*)(&P[r0 + ll][kp * 32 + quad * 8]);
      short8 a1 = *(const short8*)(&P[r0 + 16 + ll][kp * 32 + quad * 8]);
      #pragma unroll
      for (int nt = 0; nt < 8; ++nt) {
        int h = hc * 128 + nt * 16 + ll;
        short8 bbv = *(const short8*)(vtb + (size_t)h * TT + kp * 32 + quad * 8);
        o[0][nt] = __builtin_amdgcn_mfma_f32_16x16x32_bf16(a0, bbv, o[0][nt], 0, 0, 0);
        o[1][nt] = __builtin_amdgcn_mfma_f32_16x16x32_bf16(a1, bbv, o[1][nt], 0, 0, 0);
      }
    }
    #pragma unroll
    for (int mt = 0; mt < 2; ++mt)
      #pragma unroll
      for (int nt = 0; nt < 8; ++nt)
        #pragma unroll
        for (int r = 0; r < 4; ++r) {
          int row = r0 + mt * 16 + quad * 4 + r;
          int h = hc * 128 + nt * 16 + ll;
          attno[(size_t)(b * TT + row) * HH + h] = f2b(o[mt][nt][r]);
        }
  }
}

// ---------------- Tag logits + softmax + loss ----------------
__global__ __launch_bounds__(256) void logits_kernel(
    const short* __restrict__ A, const short* __restrict__ Wt, const float* __restrict__ btg,
    const int* __restrict__ tag_ids, const float* __restrict__ tmask,
    float* __restrict__ prob, float* __restrict__ lsum, float* __restrict__ lcnt) {
  int wave = threadIdx.x >> 6, lane = threadIdx.x & 63, ll = lane & 15, quad = lane >> 4;
  int m0 = blockIdx.x * 64 + wave * 16;
  f32x4 acc[5] = {};
  const short* ap = A + (size_t)(m0 + ll) * HH + quad * 8;
  #pragma unroll 4
  for (int ks = 0; ks < 16; ++ks) {
    short8 a = *(const short8*)(ap + ks * 32);
    #pragma unroll
    for (int ct = 0; ct < 5; ++ct)
      acc[ct] = __builtin_amdgcn_mfma_f32_16x16x32_bf16(a, *(const short8*)(Wt + (size_t)(ct * 16 + ll) * HH + ks * 32 + quad * 8), acc[ct], 0, 0, 0);
  }
  float bv[5];
  #pragma unroll
  for (int ct = 0; ct < 5; ++ct) bv[ct] = btg[ct * 16 + ll];
  #pragma unroll
  for (int r = 0; r < 4; ++r) {
    int row = m0 + quad * 4 + r;
    float madd = (1.f - tmask[row]) * (-1e32f);
    int tg = tag_ids[row];
    float v[5]; float mx = -3e38f; float logit_t = 0.f;
    #pragma unroll
    for (int ct = 0; ct < 5; ++ct) {
      int c = ct * 16 + ll;
      float x = (c < NTAG) ? (acc[ct][r] + bv[ct] + madd) : -3e38f;
      if (c == tg) logit_t = x;
      v[ct] = x; mx = fmaxf(mx, x);
    }
    #pragma unroll
    for (int off = 1; off < 16; off <<= 1) mx = fmaxf(mx, __shfl_xor(mx, off));
    float sum = 0.f;
    #pragma unroll
    for (int ct = 0; ct < 5; ++ct) { v[ct] = __expf(v[ct] - mx); sum += v[ct]; }
    #pragma unroll
    for (int off = 1; off < 16; off <<= 1) sum += __shfl_xor(sum, off);
    float inv = 1.f / sum;
    #pragma unroll
    for (int ct = 0; ct < 5; ++ct) {
      int c = ct * 16 + ll;
      if (c < NTAG) prob[(size_t)row * NTAG + c] = v[ct] * inv;
    }
    if (tg != 0 && ll == (tg & 15)) {
      float nll = (mx + __logf(sum)) - logit_t;
      atomicAdd(lsum, nll);
      atomicAdd(lcnt, 1.0f);
    }
  }
}

__global__ void finalize_loss(const float* __restrict__ lacc, float* __restrict__ outp) {
  outp[0] = lacc[0] / fmaxf(lacc[1], 1.f);
}

// ---------------- host ----------------
extern "C" void kernel_launch(void* const* d_in, const int* in_sizes, int n_in,
                              void* d_out, int out_size, void* d_ws, size_t ws_size,
                              hipStream_t stream) {
  const int*   input_ids = (const int*)d_in[0];
  const int*   tag_ids   = (const int*)d_in[1];
  const float* tag_mask  = (const float*)d_in[2];
  const float* emb   = (const float*)d_in[3];
  const float* eWih  = (const float*)d_in[4];
  const float* eWhh  = (const float*)d_in[5];
  const float* ebih  = (const float*)d_in[6];
  const float* ebhh  = (const float*)d_in[7];
  const float* dWih  = (const float*)d_in[8];
  const float* dWhh  = (const float*)d_in[9];
  const float* dbih  = (const float*)d_in[10];
  const float* dbhh  = (const float*)d_in[11];
  const float* ln_g  = (const float*)d_in[12];
  const float* ln_b  = (const float*)d_in[13];
  const float* Wq = (const float*)d_in[14];
  const float* bq = (const float*)d_in[15];
  const float* Wk = (const float*)d_in[16];
  const float* bk = (const float*)d_in[17];
  const float* Wv = (const float*)d_in[18];
  const float* bv = (const float*)d_in[19];
  const float* Wtag = (const float*)d_in[20];
  const float* btag = (const float*)d_in[21];
  float* outp = (float*)d_out;

  char* ws = (char*)d_ws;
  size_t off = 0;
  auto alloc = [&](size_t bytes) { char* p = ws + off; off += (bytes + 255) & ~(size_t)255; return p; };
  short* WcatE = (short*)alloc((size_t)4 * 2048 * 1024 * 2);
  short* WcatD = (short*)alloc((size_t)4 * 2048 * 1024 * 2);
  float* bE    = (float*)alloc(4 * 2048 * 4);
  float* bD    = (float*)alloc(4 * 2048 * 4);
  short* Wqkv  = (short*)alloc((size_t)1536 * 512 * 2);
  float* bqkv  = (float*)alloc(1536 * 4);
  short* Wt    = (short*)alloc((size_t)80 * 512 * 2);
  float* btg   = (float*)alloc(80 * 4);
  short* X     = (short*)alloc((size_t)TT * BB * HH * 2);   // embeddings; later reused as Vt
  short* hE    = (short*)alloc((size_t)2 * LLAY * BB * HH * 2);
  short* hD    = (short*)alloc((size_t)2 * LLAY * BB * HH * 2);
  float* cbuf  = (float*)alloc((size_t)LLAY * BB * HH * 4);
  short* dec   = (short*)alloc((size_t)BB * TT * HH * 2);
  short* qkv   = (short*)alloc((size_t)BB * TT * 1536 * 2);
  short* attno = (short*)alloc((size_t)BB * TT * HH * 2);
  float* lacc  = (float*)alloc(256);
  unsigned* flags = (unsigned*)alloc(512 * 4);

  hipMemsetAsync(hE, 0, (size_t)2 * LLAY * BB * HH * 2, stream);
  hipMemsetAsync(cbuf, 0, (size_t)LLAY * BB * HH * 4, stream);
  hipMemsetAsync(lacc, 0, 8, stream);
  hipMemsetAsync(flags, 0, 512 * 4, stream);

  prep_lstm_w<<<65536, 256, 0, stream>>>(eWih, eWhh, dWih, dWhh, WcatE, WcatD);
  prep_misc<<<231, 256, 0, stream>>>(ebih, ebhh, dbih, dbhh, bq, bk, bv, Wtag, btag,
                                     bE, bD, bqkv, Wt, btg);
  prep_qkvw<<<3072, 256, 0, stream>>>(Wq, Wk, Wv, Wqkv);
  prep_emb<<<65536, 256, 0, stream>>>(input_ids, emb, X);

  {
    void* cargs[10];
    cargs[0] = (void*)&WcatE; cargs[1] = (void*)&WcatD;
    cargs[2] = (void*)&bE;    cargs[3] = (void*)&bD;
    cargs[4] = (void*)&X;     cargs[5] = (void*)&hE;
    cargs[6] = (void*)&hD;    cargs[7] = (void*)&cbuf;
    cargs[8] = (void*)&dec;   cargs[9] = (void*)&flags;
    hipLaunchCooperativeKernel((const void*)lstm_coop, dim3(512), dim3(256),
                               cargs, 0, stream);
  }

  ln_kernel<<<8192, 256, 0, stream>>>(dec, ln_g, ln_b);
  gemm_qkv<<<dim3(512, 24), 256, 0, stream>>>(dec, Wqkv, bqkv, qkv);
  vtrans<<<65536, 256, 0, stream>>>(qkv, X);            // X reused as Vt[b][h][t]
  attn_kernel<<<256, 256, 0, stream>>>(qkv, X, attno);
  logits_kernel<<<512, 256, 0, stream>>>(attno, Wt, btg, tag_ids, tag_mask,
                                         outp, lacc, lacc + 1);
  finalize_loss<<<1, 1, 0, stream>>>(lacc, outp + (size_t)BB * TT * NTAG);
}

// Round 6
// 13522.374 us; speedup vs baseline: 1.1175x; 1.1175x over previous
//
#include <hip/hip_runtime.h>
#include <cstdint>

// Problem dims
#define BB   256
#define TT   128
#define HH   512
#define LLAY 4
#define NTAG 74
#define G4   2048   // 4*H
#define K2   1024   // 2*H

typedef short short8 __attribute__((ext_vector_type(8)));
typedef float f32x4  __attribute__((ext_vector_type(4)));
typedef int   i32x4  __attribute__((ext_vector_type(4)));

__device__ __forceinline__ float b2f(short s) {
  union { unsigned u; float f; } c; c.u = ((unsigned)(unsigned short)s) << 16; return c.f;
}
__device__ __forceinline__ short f2b(float f) {
  union { float f; unsigned u; } c; c.f = f;
  unsigned u = c.u + 0x7fffu + ((c.u >> 16) & 1u);
  return (short)(u >> 16);
}
__device__ __forceinline__ float sigm(float x) { return 1.f / (1.f + __expf(-x)); }
__device__ __forceinline__ float tanh_f(float x) {
  x = fminf(fmaxf(x, -15.f), 15.f);
  float e = __expf(2.f * x);
  return (e - 1.f) / (e + 1.f);
}

// ---- coherent (MALL) access helpers: bypass L1/L2 with sc0 sc1 ----
__device__ __forceinline__ void ld8_sc(i32x4* d,
    const short* a0, const short* a1, const short* a2, const short* a3,
    const short* a4, const short* a5, const short* a6, const short* a7) {
  asm volatile(
      "global_load_dwordx4 %0, %8, off sc0 sc1\n\t"
      "global_load_dwordx4 %1, %9, off sc0 sc1\n\t"
      "global_load_dwordx4 %2, %10, off sc0 sc1\n\t"
      "global_load_dwordx4 %3, %11, off sc0 sc1\n\t"
      "global_load_dwordx4 %4, %12, off sc0 sc1\n\t"
      "global_load_dwordx4 %5, %13, off sc0 sc1\n\t"
      "global_load_dwordx4 %6, %14, off sc0 sc1\n\t"
      "global_load_dwordx4 %7, %15, off sc0 sc1\n\t"
      "s_waitcnt vmcnt(0)"
      : "=&v"(d[0]), "=&v"(d[1]), "=&v"(d[2]), "=&v"(d[3]),
        "=&v"(d[4]), "=&v"(d[5]), "=&v"(d[6]), "=&v"(d[7])
      : "v"(a0), "v"(a1), "v"(a2), "v"(a3), "v"(a4), "v"(a5), "v"(a6), "v"(a7)
      : "memory");
}
__device__ __forceinline__ void vm_wait0() {
  asm volatile("s_waitcnt vmcnt(0)" ::: "memory");
}
__device__ __forceinline__ void st2_sc(short* p, int v) {
  asm volatile("global_store_short %0, %1, off sc0 sc1" :: "v"(p), "v"(v) : "memory");
}

// Atomic-counter grid barrier through MALL.
// Arrival: one device-scope atomicAdd per block (serializes at the MALL —
// no flag-array scan). The last arriver broadcasts the phase into 8 padded
// release lines; every block's lane 0 polls ONE line with s_sleep backoff.
// Ordering: each block's data stores are drained (vmcnt) before its atomic;
// the releaser is a participant, so release happens-after all arrivals.
__device__ __forceinline__ void gbar(unsigned* cnt, unsigned* rel, int target) {
  vm_wait0();
  __syncthreads();    // every wave's vmem drained before arrival
  if (threadIdx.x == 0) {
    unsigned old = atomicAdd(cnt, 1u);
    if (old == (unsigned)(512 * target - 1)) {
      int t = target;
      #pragma unroll
      for (int i = 0; i < 8; ++i)
        asm volatile("global_store_dword %0, %1, off sc0 sc1"
                     :: "v"(rel + i * 64), "v"(t) : "memory");
    }
    const unsigned* p = rel + (blockIdx.x & 7) * 64;
    for (;;) {
      unsigned r;
      asm volatile("global_load_dword %0, %1, off sc0 sc1\n\ts_waitcnt vmcnt(0)"
                   : "=&v"(r) : "v"(p) : "memory");
      if ((int)r >= target) break;
      __builtin_amdgcn_s_sleep(1);
    }
  }
  __syncthreads();
}

// ---------------- prep kernels ----------------

// Wcat[which][l][n'][k] bf16, n' = (h>>4)*64 + gate*16 + (h&15); k<512 from Wih, else Whh
__global__ void prep_lstm_w(const float* __restrict__ eWih, const float* __restrict__ eWhh,
                            const float* __restrict__ dWih, const float* __restrict__ dWhh,
                            short* __restrict__ WcatE, short* __restrict__ WcatD) {
  int idx = blockIdx.x * 256 + threadIdx.x;   // 2*4*2048*1024 = 2^24 exact
  int k = idx & 1023;
  int np = (idx >> 10) & 2047;
  int l = (idx >> 21) & 3;
  int which = idx >> 23;
  int gate = (np >> 4) & 3;
  int h = ((np >> 6) << 4) | (np & 15);
  int srow = gate * HH + h;
  const float* Wih = which ? dWih : eWih;
  const float* Whh = which ? dWhh : eWhh;
  float v = (k < HH) ? Wih[(size_t)(l * G4 + srow) * HH + k]
                     : Whh[(size_t)(l * G4 + srow) * HH + (k - HH)];
  short* dst = which ? WcatD : WcatE;
  dst[(size_t)(l * G4 + np) * K2 + k] = f2b(v);
}

__global__ void prep_misc(const float* __restrict__ ebih, const float* __restrict__ ebhh,
                          const float* __restrict__ dbih, const float* __restrict__ dbhh,
                          const float* __restrict__ bq, const float* __restrict__ bk,
                          const float* __restrict__ bv,
                          const float* __restrict__ Wtag, const float* __restrict__ btag,
                          float* __restrict__ bE, float* __restrict__ bD,
                          float* __restrict__ bqkv, short* __restrict__ Wt,
                          float* __restrict__ btg) {
  int idx = blockIdx.x * 256 + threadIdx.x;
  if (idx < 16384) {                                    // combined biases, permuted
    int np = idx & 2047; int l = (idx >> 11) & 3; int which = idx >> 13;
    int gate = (np >> 4) & 3; int h = ((np >> 6) << 4) | (np & 15);
    int srow = gate * HH + h;
    const float* bih = which ? dbih : ebih; const float* bhh = which ? dbhh : ebhh;
    (which ? bD : bE)[l * G4 + np] = bih[l * G4 + srow] + bhh[l * G4 + srow];
  } else if (idx < 16384 + 1536) {
    int j = idx - 16384;
    bqkv[j] = (j < 512) ? bq[j] : (j < 1024 ? bk[j - 512] : bv[j - 1024]);
  } else if (idx < 16384 + 1536 + 80 * 512) {           // Wt[80][512] (zero-padded rows)
    int j = idx - (16384 + 1536);
    int c = j >> 9, k = j & 511;
    Wt[j] = f2b(c < NTAG ? Wtag[(size_t)c * HH + k] : 0.f);
  } else if (idx < 16384 + 1536 + 80 * 512 + 80) {
    int c = idx - (16384 + 1536 + 80 * 512);
    btg[c] = (c < NTAG) ? btag[c] : 0.f;
  }
}

__global__ void prep_qkvw(const float* __restrict__ Wq, const float* __restrict__ Wk,
                          const float* __restrict__ Wv, short* __restrict__ Wqkv) {
  int idx = blockIdx.x * 256 + threadIdx.x;   // 1536*512
  int k = idx & 511; int n = idx >> 9;
  const float* W = (n < 512) ? Wq : (n < 1024 ? Wk : Wv);
  Wqkv[idx] = f2b(W[(size_t)(n & 511) * HH + k]);
}

__global__ void prep_emb(const int* __restrict__ ids, const float* __restrict__ emb,
                         short* __restrict__ X) {
  int idx = blockIdx.x * 256 + threadIdx.x;   // T*B*H = 2^24, layout [t][b][h]
  int h = idx & 511; int b = (idx >> 9) & 255; int t = idx >> 17;
  int tok = ids[b * TT + t];
  X[idx] = f2b(emb[(size_t)tok * HH + h]);
}

// ---------------- persistent LSTM: encoder wavefront + decoder ----------------
// 512 blocks x 256 threads, co-resident (2 blocks/CU). Atomic-counter MALL
// barrier; h-state via sc0sc1; weights L2-cached with XCD-affine tile
// ownership (bid%8 == XCD under round-robin dispatch) so each XCD's weight
// working set (~2 MB) stays resident in its 4 MiB L2 across all phases.
__global__ __launch_bounds__(256, 2) void lstm_coop(
    const short* __restrict__ WE, const short* __restrict__ WD,
    const float* __restrict__ bEc, const float* __restrict__ bDc,
    const short* __restrict__ X, short* __restrict__ hE,
    short* __restrict__ hD, float* __restrict__ cbuf, short* __restrict__ dec,
    unsigned* __restrict__ cnt, unsigned* __restrict__ rel) {
  const int bid = blockIdx.x;
  const int wave = threadIdx.x >> 6, lane = threadIdx.x & 63;
  const int ll = lane & 15, quad = lane >> 4;
  const size_t SL = (size_t)BB * HH;
  const int xcd = bid & 7, slot = bid >> 3;

  __shared__ __align__(16) char smem[70656];
  short* eA = (short*)smem;                 // encoder: [4 waves][16 rows][520]
  short* dA = (short*)smem;                 // decoder: [16 rows][1040]
  float* part = (float*)(smem + 33280);     // decoder: [4][4][16][16]

  int phase = 0;

  // ================= encoder wavefront: 131 diagonals =================
  {
    // XCD-affine: layer = xcd/2; n-half = xcd&1. Per-XCD weights: 16x128KB = 2MB.
    const int l = xcd >> 1;
    const int tm = slot >> 4, tn = (xcd & 1) * 16 + (slot & 15);
    const int m0 = tm * 64, n0 = tn * 64;
    short* Aw = eA + wave * 16 * 520;
    for (int d = 0; d < TT + LLAY - 1; ++d) {
      const int t = d - l;
      if (t >= 0 && t < TT) {
        const short* W = WE + (size_t)l * G4 * K2;
        const float* bcp = bEc + l * G4;
        const short* hin = hE + ((size_t)((d - 1) & 1) * LLAY + l) * SL;
        const short* xs = (l == 0) ? (X + (size_t)t * SL)
                                   : (hE + ((size_t)((d - 1) & 1) * LLAY + (l - 1)) * SL);
        short* hout = hE + ((size_t)(d & 1) * LLAY + l) * SL;
        short* hout2 = (t == TT - 1) ? (hD + ((size_t)LLAY + l) * SL) : nullptr;
        float* cb = cbuf + (size_t)l * SL;

        f32x4 acc[4] = {};
        const short* bp = W + (size_t)(n0 + ll) * K2 + quad * 8;

        // ---- k-half 0: x (stage via MALL, wave-private LDS region) ----
        {
          i32x4 dr[8];
          const short* g = xs + (size_t)(m0 + wave * 16) * HH + lane * 8;
          ld8_sc(dr, g, g + HH, g + 2 * HH, g + 3 * HH,
                 g + 4 * HH, g + 5 * HH, g + 6 * HH, g + 7 * HH);
          #pragma unroll
          for (int i = 0; i < 8; ++i) *(i32x4*)(Aw + i * 520 + lane * 8) = dr[i];
          const short* g2 = g + 8 * HH;
          ld8_sc(dr, g2, g2 + HH, g2 + 2 * HH, g2 + 3 * HH,
                 g2 + 4 * HH, g2 + 5 * HH, g2 + 6 * HH, g2 + 7 * HH);
          #pragma unroll
          for (int i = 0; i < 8; ++i) *(i32x4*)(Aw + (8 + i) * 520 + lane * 8) = dr[i];
        }
        #pragma unroll 4
        for (int ks = 0; ks < 16; ++ks) {
          short8 a = *(const short8*)(Aw + ll * 520 + ks * 32 + quad * 8);
          #pragma unroll
          for (int f = 0; f < 4; ++f)
            acc[f] = __builtin_amdgcn_mfma_f32_16x16x32_bf16(
                a, *(const short8*)(bp + (size_t)f * 16 * K2 + ks * 32), acc[f], 0, 0, 0);
        }
        // ---- k-half 1: h ----
        {
          i32x4 dr[8];
          const short* g = hin + (size_t)(m0 + wave * 16) * HH + lane * 8;
          ld8_sc(dr, g, g + HH, g + 2 * HH, g + 3 * HH,
                 g + 4 * HH, g + 5 * HH, g + 6 * HH, g + 7 * HH);
          #pragma unroll
          for (int i = 0; i < 8; ++i) *(i32x4*)(Aw + i * 520 + lane * 8) = dr[i];
          const short* g2 = g + 8 * HH;
          ld8_sc(dr, g2, g2 + HH, g2 + 2 * HH, g2 + 3 * HH,
                 g2 + 4 * HH, g2 + 5 * HH, g2 + 6 * HH, g2 + 7 * HH);
          #pragma unroll
          for (int i = 0; i < 8; ++i) *(i32x4*)(Aw + (8 + i) * 520 + lane * 8) = dr[i];
        }
        #pragma unroll 4
        for (int ks = 0; ks < 16; ++ks) {
          short8 a = *(const short8*)(Aw + ll * 520 + ks * 32 + quad * 8);
          #pragma unroll
          for (int f = 0; f < 4; ++f)
            acc[f] = __builtin_amdgcn_mfma_f32_16x16x32_bf16(
                a, *(const short8*)(bp + 512 + (size_t)f * 16 * K2 + ks * 32), acc[f], 0, 0, 0);
        }
        // ---- fused LSTM cell epilogue (c is block-private: cached) ----
        const float bg0 = bcp[n0 + ll], bg1 = bcp[n0 + 16 + ll];
        const float bg2 = bcp[n0 + 32 + ll], bg3 = bcp[n0 + 48 + ll];
        const int hcol = tn * 16 + ll;
        #pragma unroll
        for (int r = 0; r < 4; ++r) {
          int row = m0 + wave * 16 + quad * 4 + r;
          float iv = acc[0][r] + bg0, fv = acc[1][r] + bg1;
          float gv = acc[2][r] + bg2, ov = acc[3][r] + bg3;
          float co = cb[(size_t)row * HH + hcol];
          float cn = sigm(fv) * co + sigm(iv) * tanh_f(gv);
          float hn = sigm(ov) * tanh_f(cn);
          cb[(size_t)row * HH + hcol] = cn;
          short hb = f2b(hn);
          st2_sc(hout + (size_t)row * HH + hcol, (int)(unsigned short)hb);
          if (hout2) st2_sc(hout2 + (size_t)row * HH + hcol, (int)(unsigned short)hb);
        }
      }
      ++phase;
      gbar(cnt, rel, phase);
    }
  }

  // push encoder's cached dirty c lines to MALL before ownership changes
  asm volatile("buffer_wbl2 sc1" ::: "memory");
  ++phase;
  gbar(cnt, rel, phase);

  // ================= decoder: 512 sequential layer-steps =================
  {
    // XCD-affine: xcd owns ntile in [xcd*4, xcd*4+4). Per-XCD weights
    // across all 4 layers: 4*4*128KB = 2MB — L2-resident for all phases.
    const int mrow = slot >> 2, ntile = xcd * 4 + (slot & 3);
    const int m0 = mrow * 16;
    for (int p = 0; p < TT * LLAY; ++p) {
      const int t = p >> 2, l = p & 3;
      const short* W = WD + (size_t)l * G4 * K2;
      const float* bcp = bDc + l * G4;
      const short* hin = hD + ((size_t)((t + 1) & 1) * LLAY + l) * SL;
      const short* xs = (l == 0) ? (hD + ((size_t)((t + 1) & 1) * LLAY + 3) * SL)
                                 : (hD + ((size_t)(t & 1) * LLAY + (l - 1)) * SL);
      short* hout = hD + ((size_t)(t & 1) * LLAY + l) * SL;
      float* cb = cbuf + (size_t)l * SL;

      // stage A = [x | h] 16 rows x 1024 via MALL into LDS (cross-wave)
      {
        i32x4 dr[8];
        const short* gx = xs + (size_t)(m0 + wave * 4) * HH + lane * 8;
        const short* gh = hin + (size_t)(m0 + wave * 4) * HH + lane * 8;
        ld8_sc(dr, gx, gx + HH, gx + 2 * HH, gx + 3 * HH,
               gh, gh + HH, gh + 2 * HH, gh + 3 * HH);
        #pragma unroll
        for (int i = 0; i < 4; ++i) *(i32x4*)(dA + (wave * 4 + i) * 1040 + lane * 8) = dr[i];
        #pragma unroll
        for (int i = 0; i < 4; ++i) *(i32x4*)(dA + (wave * 4 + i) * 1040 + 512 + lane * 8) = dr[4 + i];
      }
      __syncthreads();

      // split-K: wave w covers k-quarter w*256 (x halves then h halves)
      f32x4 acc[4] = {};
      const short* bp = W + (size_t)(ntile * 64 + ll) * K2 + wave * 256 + quad * 8;
      #pragma unroll
      for (int ks = 0; ks < 8; ++ks) {
        short8 a = *(const short8*)(dA + ll * 1040 + wave * 256 + ks * 32 + quad * 8);
        #pragma unroll
        for (int f = 0; f < 4; ++f)
          acc[f] = __builtin_amdgcn_mfma_f32_16x16x32_bf16(
              a, *(const short8*)(bp + (size_t)f * 16 * K2 + ks * 32), acc[f], 0, 0, 0);
      }
      #pragma unroll
      for (int f = 0; f < 4; ++f)
        #pragma unroll
        for (int r = 0; r < 4; ++r)
          part[((wave * 4 + f) * 16 + quad * 4 + r) * 16 + ll] = acc[f][r];
      __syncthreads();
      {
        const int row = threadIdx.x >> 4, hc = threadIdx.x & 15;
        float g4v[4];
        #pragma unroll
        for (int f = 0; f < 4; ++f) {
          float s = bcp[ntile * 64 + f * 16 + hc];
          #pragma unroll
          for (int w = 0; w < 4; ++w) s += part[((w * 4 + f) * 16 + row) * 16 + hc];
          g4v[f] = s;
        }
        const int brow = m0 + row, hcol = ntile * 16 + hc;
        float co = cb[(size_t)brow * HH + hcol];
        float cn = sigm(g4v[1]) * co + sigm(g4v[0]) * tanh_f(g4v[2]);
        float hn = sigm(g4v[3]) * tanh_f(cn);
        cb[(size_t)brow * HH + hcol] = cn;
        short hb = f2b(hn);
        st2_sc(hout + (size_t)brow * HH + hcol, (int)(unsigned short)hb);
        if (l == 3) dec[((size_t)brow * TT + t) * HH + hcol] = hb;
      }
      ++phase;
      gbar(cnt, rel, phase);
    }
  }
}

// ---------------- LayerNorm (in place, bf16) ----------------
__global__ __launch_bounds__(256) void ln_kernel(short* __restrict__ x,
                                                 const float* __restrict__ g,
                                                 const float* __restrict__ bta) {
  int wave = threadIdx.x >> 6, lane = threadIdx.x & 63;
  int row = blockIdx.x * 4 + wave;
  short8 xv = *(const short8*)(x + (size_t)row * HH + lane * 8);
  float xs[8]; float s = 0.f, ss = 0.f;
  #pragma unroll
  for (int j = 0; j < 8; ++j) { xs[j] = b2f(xv[j]); s += xs[j]; ss += xs[j] * xs[j]; }
  #pragma unroll
  for (int off = 1; off < 64; off <<= 1) { s += __shfl_xor(s, off); ss += __shfl_xor(ss, off); }
  float mu = s * (1.f / HH);
  float var = ss * (1.f / HH) - mu * mu;
  float rs = rsqrtf(var + 1e-5f);
  short8 ov;
  #pragma unroll
  for (int j = 0; j < 8; ++j) {
    int k = lane * 8 + j;
    ov[j] = f2b((xs[j] - mu) * rs * g[k] + bta[k]);
  }
  *(short8*)(x + (size_t)row * HH + lane * 8) = ov;
}

// ---------------- QKV projection GEMM ----------------
__global__ __launch_bounds__(256) void gemm_qkv(const short* __restrict__ A,
                                                const short* __restrict__ Wn,
                                                const float* __restrict__ bias,
                                                short* __restrict__ out) {
  int wave = threadIdx.x >> 6, lane = threadIdx.x & 63, ll = lane & 15, quad = lane >> 4;
  int m0 = blockIdx.x * 64 + wave * 16;
  int n0 = blockIdx.y * 64;
  f32x4 acc[4] = {};
  const short* ap = A + (size_t)(m0 + ll) * HH + quad * 8;
  const short* bp = Wn + (size_t)(n0 + ll) * HH + quad * 8;
  #pragma unroll 4
  for (int ks = 0; ks < 16; ++ks) {
    short8 a = *(const short8*)(ap + ks * 32);
    #pragma unroll
    for (int f = 0; f < 4; ++f)
      acc[f] = __builtin_amdgcn_mfma_f32_16x16x32_bf16(a, *(const short8*)(bp + f * 16 * HH + ks * 32), acc[f], 0, 0, 0);
  }
  #pragma unroll
  for (int f = 0; f < 4; ++f) {
    int n = n0 + f * 16 + ll;
    float bv = bias[n];
    #pragma unroll
    for (int r = 0; r < 4; ++r) {
      int row = m0 + quad * 4 + r;
      out[(size_t)row * 1536 + n] = f2b(acc[f][r] + bv);
    }
  }
}

// ---------------- V transpose: Vt[b][h][t] ----------------
__global__ void vtrans(const short* __restrict__ qkv, short* __restrict__ vt) {
  int idx = blockIdx.x * 256 + threadIdx.x;  // 256*512*128 = 2^24
  int t = idx & 127, h = (idx >> 7) & 511, b = idx >> 16;
  vt[idx] = qkv[(size_t)(b * TT + t) * 1536 + 1024 + h];
}

// ---------------- Fused attention per batch ----------------
__global__ __launch_bounds__(256) void attn_kernel(const short* __restrict__ qkv,
                                                   const short* __restrict__ vt,
                                                   short* __restrict__ attno) {
  int b = blockIdx.x;
  int wave = threadIdx.x >> 6, lane = threadIdx.x & 63, ll = lane & 15, quad = lane >> 4;
  __shared__ __align__(16) short P[128][136];
  const short* qb = qkv + (size_t)b * TT * 1536;
  int r0 = wave * 32;

  f32x4 s[2][8] = {};
  for (int ks = 0; ks < 16; ++ks) {
    short8 a0 = *(const short8*)(qb + (size_t)(r0 + ll) * 1536 + ks * 32 + quad * 8);
    short8 a1 = *(const short8*)(qb + (size_t)(r0 + 16 + ll) * 1536 + ks * 32 + quad * 8);
    #pragma unroll
    for (int ct = 0; ct < 8; ++ct) {
      short8 bbv = *(const short8*)(qb + (size_t)(ct * 16 + ll) * 1536 + 512 + ks * 32 + quad * 8);
      s[0][ct] = __builtin_amdgcn_mfma_f32_16x16x32_bf16(a0, bbv, s[0][ct], 0, 0, 0);
      s[1][ct] = __builtin_amdgcn_mfma_f32_16x16x32_bf16(a1, bbv, s[1][ct], 0, 0, 0);
    }
  }
  const float scale = 0.04419417382415922f;  // 1/sqrt(512)
  #pragma unroll
  for (int mt = 0; mt < 2; ++mt) {
    #pragma unroll
    for (int r = 0; r < 4; ++r) {
      float v[8]; float mx = -1e30f;
      #pragma unroll
      for (int ct = 0; ct < 8; ++ct) { v[ct] = s[mt][ct][r] * scale; mx = fmaxf(mx, v[ct]); }
      #pragma unroll
      for (int off = 1; off < 16; off <<= 1) mx = fmaxf(mx, __shfl_xor(mx, off));
      float sum = 0.f;
      #pragma unroll
      for (int ct = 0; ct < 8; ++ct) { v[ct] = __expf(v[ct] - mx); sum += v[ct]; }
      #pragma unroll
      for (int off = 1; off < 16; off <<= 1) sum += __shfl_xor(sum, off);
      float inv = 1.f / sum;
      int row = r0 + mt * 16 + quad * 4 + r;
      #pragma unroll
      for (int ct = 0; ct < 8; ++ct) P[row][ct * 16 + ll] = f2b(v[ct] * inv);
    }
  }
  __syncthreads();

  const short* vtb = vt + (size_t)b * HH * TT;
  for (int hc = 0; hc < 4; ++hc) {
    f32x4 o[2][8] = {};
    #pragma unroll
    for (int kp = 0; kp < 4; ++kp) {
      short8 a0 = *(const short8*)(&P[r0 + ll][kp * 32 + quad * 8]);
      short8 a1 = *(const short8*)(&P[r0 + 16 + ll][kp * 32 + quad * 8]);
      #pragma unroll
      for (int nt = 0; nt < 8; ++nt) {
        int h = hc * 128 + nt * 16 + ll;
        short8 bbv = *(const short8*)(vtb + (size_t)h * TT + kp * 32 + quad * 8);
        o[0][nt] = __builtin_amdgcn_mfma_f32_16x16x32_bf16(a0, bbv, o[0][nt], 0, 0, 0);
        o[1][nt] = __builtin_amdgcn_mfma_f32_16x16x32_bf16(a1, bbv, o[1][nt], 0, 0, 0);
      }
    }
    #pragma unroll
    for (int mt = 0; mt < 2; ++mt)
      #pragma unroll
      for (int nt = 0; nt < 8; ++nt)
        #pragma unroll
        for (int r = 0; r < 4; ++r) {
          int row = r0 + mt * 16 + quad * 4 + r;
          int h = hc * 128 + nt * 16 + ll;
          attno[(size_t)(b * TT + row) * HH + h] = f2b(o[mt][nt][r]);
        }
  }
}

// ---------------- Tag logits + softmax + loss ----------------
__global__ __launch_bounds__(256) void logits_kernel(
    const short* __restrict__ A, const short* __restrict__ Wt, const float* __restrict__ btg,
    const int* __restrict__ tag_ids, const float* __restrict__ tmask,
    float* __restrict__ prob, float* __restrict__ lsum, float* __restrict__ lcnt) {
  int wave = threadIdx.x >> 6, lane = threadIdx.x & 63, ll = lane & 15, quad = lane >> 4;
  int m0 = blockIdx.x * 64 + wave * 16;
  f32x4 acc[5] = {};
  const short* ap = A + (size_t)(m0 + ll) * HH + quad * 8;
  #pragma unroll 4
  for (int ks = 0; ks < 16; ++ks) {
    short8 a = *(const short8*)(ap + ks * 32);
    #pragma unroll
    for (int ct = 0; ct < 5; ++ct)
      acc[ct] = __builtin_amdgcn_mfma_f32_16x16x32_bf16(a, *(const short8*)(Wt + (size_t)(ct * 16 + ll) * HH + ks * 32 + quad * 8), acc[ct], 0, 0, 0);
  }
  float bv[5];
  #pragma unroll
  for (int ct = 0; ct < 5; ++ct) bv[ct] = btg[ct * 16 + ll];
  #pragma unroll
  for (int r = 0; r < 4; ++r) {
    int row = m0 + quad * 4 + r;
    float madd = (1.f - tmask[row]) * (-1e32f);
    int tg = tag_ids[row];
    float v[5]; float mx = -3e38f; float logit_t = 0.f;
    #pragma unroll
    for (int ct = 0; ct < 5; ++ct) {
      int c = ct * 16 + ll;
      float x = (c < NTAG) ? (acc[ct][r] + bv[ct] + madd) : -3e38f;
      if (c == tg) logit_t = x;
      v[ct] = x; mx = fmaxf(mx, x);
    }
    #pragma unroll
    for (int off = 1; off < 16; off <<= 1) mx = fmaxf(mx, __shfl_xor(mx, off));
    float sum = 0.f;
    #pragma unroll
    for (int ct = 0; ct < 5; ++ct) { v[ct] = __expf(v[ct] - mx); sum += v[ct]; }
    #pragma unroll
    for (int off = 1; off < 16; off <<= 1) sum += __shfl_xor(sum, off);
    float inv = 1.f / sum;
    #pragma unroll
    for (int ct = 0; ct < 5; ++ct) {
      int c = ct * 16 + ll;
      if (c < NTAG) prob[(size_t)row * NTAG + c] = v[ct] * inv;
    }
    if (tg != 0 && ll == (tg & 15)) {
      float nll = (mx + __logf(sum)) - logit_t;
      atomicAdd(lsum, nll);
      atomicAdd(lcnt, 1.0f);
    }
  }
}

__global__ void finalize_loss(const float* __restrict__ lacc, float* __restrict__ outp) {
  outp[0] = lacc[0] / fmaxf(lacc[1], 1.f);
}

// ---------------- host ----------------
extern "C" void kernel_launch(void* const* d_in, const int* in_sizes, int n_in,
                              void* d_out, int out_size, void* d_ws, size_t ws_size,
                              hipStream_t stream) {
  const int*   input_ids = (const int*)d_in[0];
  const int*   tag_ids   = (const int*)d_in[1];
  const float* tag_mask  = (const float*)d_in[2];
  const float* emb   = (const float*)d_in[3];
  const float* eWih  = (const float*)d_in[4];
  const float* eWhh  = (const float*)d_in[5];
  const float* ebih  = (const float*)d_in[6];
  const float* ebhh  = (const float*)d_in[7];
  const float* dWih  = (const float*)d_in[8];
  const float* dWhh  = (const float*)d_in[9];
  const float* dbih  = (const float*)d_in[10];
  const float* dbhh  = (const float*)d_in[11];
  const float* ln_g  = (const float*)d_in[12];
  const float* ln_b  = (const float*)d_in[13];
  const float* Wq = (const float*)d_in[14];
  const float* bq = (const float*)d_in[15];
  const float* Wk = (const float*)d_in[16];
  const float* bk = (const float*)d_in[17];
  const float* Wv = (const float*)d_in[18];
  const float* bv = (const float*)d_in[19];
  const float* Wtag = (const float*)d_in[20];
  const float* btag = (const float*)d_in[21];
  float* outp = (float*)d_out;

  char* ws = (char*)d_ws;
  size_t off = 0;
  auto alloc = [&](size_t bytes) { char* p = ws + off; off += (bytes + 255) & ~(size_t)255; return p; };
  short* WcatE = (short*)alloc((size_t)4 * 2048 * 1024 * 2);
  short* WcatD = (short*)alloc((size_t)4 * 2048 * 1024 * 2);
  float* bE    = (float*)alloc(4 * 2048 * 4);
  float* bD    = (float*)alloc(4 * 2048 * 4);
  short* Wqkv  = (short*)alloc((size_t)1536 * 512 * 2);
  float* bqkv  = (float*)alloc(1536 * 4);
  short* Wt    = (short*)alloc((size_t)80 * 512 * 2);
  float* btg   = (float*)alloc(80 * 4);
  short* X     = (short*)alloc((size_t)TT * BB * HH * 2);   // embeddings; later reused as Vt
  short* hE    = (short*)alloc((size_t)2 * LLAY * BB * HH * 2);
  short* hD    = (short*)alloc((size_t)2 * LLAY * BB * HH * 2);
  float* cbuf  = (float*)alloc((size_t)LLAY * BB * HH * 4);
  short* dec   = (short*)alloc((size_t)BB * TT * HH * 2);
  short* qkv   = (short*)alloc((size_t)BB * TT * 1536 * 2);
  short* attno = (short*)alloc((size_t)BB * TT * HH * 2);
  float* lacc  = (float*)alloc(256);
  unsigned* cnt = (unsigned*)alloc(256);
  unsigned* rel = (unsigned*)alloc(8 * 64 * 4);

  hipMemsetAsync(hE, 0, (size_t)2 * LLAY * BB * HH * 2, stream);
  hipMemsetAsync(cbuf, 0, (size_t)LLAY * BB * HH * 4, stream);
  hipMemsetAsync(lacc, 0, 8, stream);
  hipMemsetAsync(cnt, 0, 256, stream);
  hipMemsetAsync(rel, 0, 8 * 64 * 4, stream);

  prep_lstm_w<<<65536, 256, 0, stream>>>(eWih, eWhh, dWih, dWhh, WcatE, WcatD);
  prep_misc<<<231, 256, 0, stream>>>(ebih, ebhh, dbih, dbhh, bq, bk, bv, Wtag, btag,
                                     bE, bD, bqkv, Wt, btg);
  prep_qkvw<<<3072, 256, 0, stream>>>(Wq, Wk, Wv, Wqkv);
  prep_emb<<<65536, 256, 0, stream>>>(input_ids, emb, X);

  {
    void* cargs[11];
    cargs[0] = (void*)&WcatE; cargs[1] = (void*)&WcatD;
    cargs[2] = (void*)&bE;    cargs[3] = (void*)&bD;
    cargs[4] = (void*)&X;     cargs[5] = (void*)&hE;
    cargs[6] = (void*)&hD;    cargs[7] = (void*)&cbuf;
    cargs[8] = (void*)&dec;   cargs[9] = (void*)&cnt;
    cargs[10] = (void*)&rel;
    hipLaunchCooperativeKernel((const void*)lstm_coop, dim3(512), dim3(256),
                               cargs, 0, stream);
  }

  ln_kernel<<<8192, 256, 0, stream>>>(dec, ln_g, ln_b);
  gemm_qkv<<<dim3(512, 24), 256, 0, stream>>>(dec, Wqkv, bqkv, qkv);
  vtrans<<<65536, 256, 0, stream>>>(qkv, X);            // X reused as Vt[b][h][t]
  attn_kernel<<<256, 256, 0, stream>>>(qkv, X, attno);
  logits_kernel<<<512, 256, 0, stream>>>(attno, Wt, btg, tag_ids, tag_mask,
                                         outp, lacc, lacc + 1);
  finalize_loss<<<1, 1, 0, stream>>>(lacc, outp + (size_t)BB * TT * NTAG);
}